// Round 1
// baseline (395.235 us; speedup 1.0000x reference)
//
#include <hip/hip_runtime.h>

// TransformerBlockQuantum: attention(Q=K=V=x) -> LN1 -> quantum FFN -> LN2
// Round 0: correctness-first MFMA implementation (fp16 inputs, fp32 accum).

#define Bq 4
#define Sq 2048
#define Eq 1024
#define Hq 16
#define DKq 64
#define FFNq 4096
#define NQq 8
#define LOG2E 1.44269504f

typedef unsigned int u32;
typedef unsigned short u16;
typedef _Float16 f16;
typedef f16 f16x8 __attribute__((ext_vector_type(8)));
typedef float f32x4 __attribute__((ext_vector_type(4)));

#if __has_builtin(__builtin_amdgcn_exp2f)
#define EXP2F __builtin_amdgcn_exp2f
#else
#define EXP2F exp2f
#endif

#define MFMA(a, b, c) __builtin_amdgcn_mfma_f32_16x16x32_f16((a), (b), (c), 0, 0, 0)

__device__ __forceinline__ u16 f2h(float x) {
  f16 t = (f16)x;
  return __builtin_bit_cast(u16, t);
}
__device__ __forceinline__ u32 pack2h(float lo, float hi) {
  return (u32)f2h(lo) | ((u32)f2h(hi) << 16);
}

union F8 { f16x8 v; u32 w[4]; u16 h[8]; };

// ---------------- fp32 -> fp16 converter (used for w2) ----------------
__global__ void k_cvt(const float* __restrict__ src, uint4* __restrict__ dst, int n8) {
  int i = blockIdx.x * 256 + threadIdx.x;
  if (i >= n8) return;
  const float4* s = (const float4*)src + 2 * (long)i;
  float4 a = s[0], b = s[1];
  uint4 r;
  r.x = pack2h(a.x, a.y);
  r.y = pack2h(a.z, a.w);
  r.z = pack2h(b.x, b.y);
  r.w = pack2h(b.z, b.w);
  dst[i] = r;
}

// ---------------- flash attention ----------------
// grid = B*H*(S/128) = 1024 blocks, 256 threads (4 waves x 32 queries).
// Per 64-key block: ST[key][q] = K x Q^T (scores transposed; softmax stats per
// lane&15 = query = same domain as O^T accumulator columns).
// O^T[d][q] += V^T x P  (P via LDS round-trip into operand layout).
__global__ __launch_bounds__(256) void k_attn(const float* __restrict__ x,
                                              float* __restrict__ attn) {
  __shared__ __align__(16) u16 lds[18432];
  u16* Kl = lds;          // [64 keys][72]  (row-major, for QK^T A-operand)
  u16* Vt = lds + 4608;   // [64 d][72]    (transposed, for PV A-operand)
  u16* Pl = lds + 9216;   // [wave*2+nt][16 q][72 keys]

  const int tid = threadIdx.x;
  const int wave = tid >> 6;
  const int lane = tid & 63;
  const int n = lane & 15;
  const int quad = lane >> 4;

  const int bx = blockIdx.x;
  const int qb = bx & 15;      // q-block of 128
  const int bh = bx >> 4;      // 0..63
  const int bb = bh >> 4;      // batch
  const int hh = bh & 15;      // head
  const long base = ((long)bb * Sq) * Eq + hh * DKq;

  // Q fragments (B-operand layout): query = lane&15, k(d) = quad*8+j (+c*32).
  // Fold the 1/sqrt(DK)=0.125 scale into Q (exact in fp16).
  F8 qf[2][2];
#pragma unroll
  for (int nt = 0; nt < 2; ++nt) {
    const int q = qb * 128 + wave * 32 + nt * 16 + n;
    const float* qp = x + base + (long)q * Eq + quad * 8;
#pragma unroll
    for (int c = 0; c < 2; ++c) {
      float4 a = *(const float4*)(qp + c * 32);
      float4 b = *(const float4*)(qp + c * 32 + 4);
      qf[nt][c].w[0] = pack2h(a.x * 0.125f, a.y * 0.125f);
      qf[nt][c].w[1] = pack2h(a.z * 0.125f, a.w * 0.125f);
      qf[nt][c].w[2] = pack2h(b.x * 0.125f, b.y * 0.125f);
      qf[nt][c].w[3] = pack2h(b.z * 0.125f, b.w * 0.125f);
    }
  }

  f32x4 O[2][4] = {};              // O^T accumulators: [nt][d-tile]
  float mrow[2] = {-1e30f, -1e30f};
  float lrow[2] = {0.f, 0.f};

  const int skey = tid >> 2;       // staging: key row 0..63
  const int sd0 = (tid & 3) * 16;  // staging: 16-element d chunk

  for (int kb = 0; kb < Sq / 64; ++kb) {
    __syncthreads();  // previous iteration's LDS reads must finish
    {
      // stage 64 keys x 64 d, fp32 -> fp16, normal + transposed copies
      const float* sp = x + base + (long)(kb * 64 + skey) * Eq + sd0;
      float4 f0 = ((const float4*)sp)[0];
      float4 f1 = ((const float4*)sp)[1];
      float4 f2 = ((const float4*)sp)[2];
      float4 f3 = ((const float4*)sp)[3];
      u32 w[8];
      w[0] = pack2h(f0.x, f0.y); w[1] = pack2h(f0.z, f0.w);
      w[2] = pack2h(f1.x, f1.y); w[3] = pack2h(f1.z, f1.w);
      w[4] = pack2h(f2.x, f2.y); w[5] = pack2h(f2.z, f2.w);
      w[6] = pack2h(f3.x, f3.y); w[7] = pack2h(f3.z, f3.w);
      uint4* kw = (uint4*)(Kl + skey * 72 + sd0);
      kw[0] = make_uint4(w[0], w[1], w[2], w[3]);
      kw[1] = make_uint4(w[4], w[5], w[6], w[7]);
#pragma unroll
      for (int i = 0; i < 8; ++i) {
        Vt[(sd0 + 2 * i) * 72 + skey] = (u16)(w[i] & 0xffffu);
        Vt[(sd0 + 2 * i + 1) * 72 + skey] = (u16)(w[i] >> 16);
      }
    }
    __syncthreads();

    // QK^T: ST[nt][mt], C-layout row = key = quad*4+reg (+mt*16), col = query = n
    f32x4 ST[2][4] = {};
#pragma unroll
    for (int mt = 0; mt < 4; ++mt) {
#pragma unroll
      for (int c = 0; c < 2; ++c) {
        f16x8 af = *(const f16x8*)(Kl + (mt * 16 + n) * 72 + c * 32 + quad * 8);
        ST[0][mt] = MFMA(af, qf[0][c].v, ST[0][mt]);
        ST[1][mt] = MFMA(af, qf[1][c].v, ST[1][mt]);
      }
    }

    // online softmax per query (= per lane&15); write P to LDS in [q][key] layout
#pragma unroll
    for (int nt = 0; nt < 2; ++nt) {
      float bm = -1e30f;
#pragma unroll
      for (int mt = 0; mt < 4; ++mt)
#pragma unroll
        for (int r = 0; r < 4; ++r) bm = fmaxf(bm, ST[nt][mt][r]);
      bm = fmaxf(bm, __shfl_xor(bm, 16));
      bm = fmaxf(bm, __shfl_xor(bm, 32));
      float mn = fmaxf(mrow[nt], bm);
      float al = EXP2F((mrow[nt] - mn) * LOG2E);
      mrow[nt] = mn;
      float rs = 0.f;
      u32* pw = (u32*)(Pl + (wave * 2 + nt) * 1152 + n * 72);
#pragma unroll
      for (int mt = 0; mt < 4; ++mt) {
        float p0 = EXP2F((ST[nt][mt][0] - mn) * LOG2E);
        float p1 = EXP2F((ST[nt][mt][1] - mn) * LOG2E);
        float p2 = EXP2F((ST[nt][mt][2] - mn) * LOG2E);
        float p3 = EXP2F((ST[nt][mt][3] - mn) * LOG2E);
        rs += (p0 + p1) + (p2 + p3);
        pw[mt * 8 + quad * 2] = pack2h(p0, p1);
        pw[mt * 8 + quad * 2 + 1] = pack2h(p2, p3);
      }
      rs += __shfl_xor(rs, 16);
      rs += __shfl_xor(rs, 32);
      lrow[nt] = lrow[nt] * al + rs;
#pragma unroll
      for (int dt = 0; dt < 4; ++dt)
#pragma unroll
        for (int r = 0; r < 4; ++r) O[nt][dt][r] *= al;
    }

    // PV: O^T[d][q] += V^T x P   (A = Vt rows, B = Pl rows; per-wave P region,
    // same-wave write->read ordering handled by compiler waitcnt)
#pragma unroll
    for (int c = 0; c < 2; ++c) {
      f16x8 pf0 = *(const f16x8*)(Pl + (wave * 2 + 0) * 1152 + n * 72 + c * 32 + quad * 8);
      f16x8 pf1 = *(const f16x8*)(Pl + (wave * 2 + 1) * 1152 + n * 72 + c * 32 + quad * 8);
#pragma unroll
      for (int dt = 0; dt < 4; ++dt) {
        f16x8 vf = *(const f16x8*)(Vt + (dt * 16 + n) * 72 + c * 32 + quad * 8);
        O[0][dt] = MFMA(vf, pf0, O[0][dt]);
        O[1][dt] = MFMA(vf, pf1, O[1][dt]);
      }
    }
  }

  // epilogue: attn[b][q][h*64 + d] = O^T[d][q] / l[q]
#pragma unroll
  for (int nt = 0; nt < 2; ++nt) {
    const float inv = 1.0f / lrow[nt];
    const int q = qb * 128 + wave * 32 + nt * 16 + n;
    float* op = attn + base + (long)q * Eq;
#pragma unroll
    for (int dt = 0; dt < 4; ++dt)
#pragma unroll
      for (int r = 0; r < 4; ++r)
        op[dt * 16 + quad * 4 + r] = O[nt][dt][r] * inv;
  }
}

// ---------------- LN1 (+residual) + quantum qout ----------------
__global__ void k_ln1(const float* __restrict__ x, const float* __restrict__ attn,
                      const float* __restrict__ g, const float* __restrict__ be,
                      const float* __restrict__ theta, float* __restrict__ hout,
                      float* __restrict__ qout) {
  const long t = blockIdx.x;
  const int tid = threadIdx.x;
  float4 xv = ((const float4*)(x + t * Eq))[tid];
  float4 av = ((const float4*)(attn + t * Eq))[tid];
  float4 v = make_float4(xv.x + av.x, xv.y + av.y, xv.z + av.z, xv.w + av.w);
  float s = v.x + v.y + v.z + v.w;
  float s2 = v.x * v.x + v.y * v.y + v.z * v.z + v.w * v.w;
#pragma unroll
  for (int o = 1; o < 64; o <<= 1) {
    s += __shfl_xor(s, o);
    s2 += __shfl_xor(s2, o);
  }
  __shared__ float red[8];
  const int wv = tid >> 6, ln = tid & 63;
  if (ln == 0) { red[wv] = s; red[4 + wv] = s2; }
  __syncthreads();
  s = red[0] + red[1] + red[2] + red[3];
  s2 = red[4] + red[5] + red[6] + red[7];
  const float mu = s * (1.f / Eq);
  const float var = s2 * (1.f / Eq) - mu * mu;
  const float rstd = rsqrtf(var + 1e-5f);
  float4 gv = ((const float4*)g)[tid];
  float4 bv = ((const float4*)be)[tid];
  float4 o;
  o.x = (v.x - mu) * rstd * gv.x + bv.x;
  o.y = (v.y - mu) * rstd * gv.y + bv.y;
  o.z = (v.z - mu) * rstd * gv.z + bv.z;
  o.w = (v.w - mu) * rstd * gv.w + bv.w;
  ((float4*)(hout + t * Eq))[tid] = o;
  if (tid < 2) {
    float hv[4] = {o.x, o.y, o.z, o.w};
#pragma unroll
    for (int i = 0; i < 4; ++i) {
      int j = tid * 4 + i;
      qout[t * NQq + j] = cosf(hv[i]) * cosf(theta[j]);
    }
  }
}

// ---------------- hid = relu(qout . w1^T + b1), fp16 out ----------------
// grid = (8192/256 t-blocks) x (4096/64 f-blocks) = 2048; wave w covers 64 t rows,
// lane = f within 64-wide slab -> coalesced 128B stores per t row.
__global__ void k_hid(const float* __restrict__ qout, const float* __restrict__ w1,
                      const float* __restrict__ b1, u16* __restrict__ hid) {
  __shared__ float qs[256][8];
  const int tid = threadIdx.x;
  const int fb = blockIdx.x & 63, tb = blockIdx.x >> 6;
  const int f0 = fb * 64, t0 = tb * 256;
  {
    const float4* qp = (const float4*)(qout + (long)(t0 + tid) * NQq);
    float4 q0 = qp[0], q1 = qp[1];
    *(float4*)&qs[tid][0] = q0;
    *(float4*)&qs[tid][4] = q1;
  }
  __syncthreads();
  const int wave = tid >> 6, lane = tid & 63;
  const int f = f0 + lane;
  const float4* wp = (const float4*)(w1 + (long)f * NQq);
  float4 wa = wp[0], wb = wp[1];
  const float bb = b1[f];
  const int trow = wave * 64;
  u16* op = hid + (long)(t0 + trow) * FFNq + f;
#pragma unroll 4
  for (int i = 0; i < 64; ++i) {
    const float* q = qs[trow + i];
    float acc = bb + q[0] * wa.x + q[1] * wa.y + q[2] * wa.z + q[3] * wa.w +
                q[4] * wb.x + q[5] * wb.y + q[6] * wb.z + q[7] * wb.w;
    acc = fmaxf(acc, 0.f);
    op[(long)i * FFNq] = f2h(acc);
  }
}

// ---------------- GEMM: ffn[8192,1024] = hid[8192,4096] x w2^T ----------------
// 128x128 tile, BK=64, 4 waves (2x2), each wave 4x4 MFMA tiles of 16x16x32.
__global__ __launch_bounds__(256) void k_gemm(const u16* __restrict__ Ah,
                                              const u16* __restrict__ Bh,
                                              float* __restrict__ C) {
  __shared__ __align__(16) u16 lds[128 * 72 * 2];
  u16* La = lds;
  u16* Lb = lds + 128 * 72;
  const int tid = threadIdx.x;
  const int wave = tid >> 6, lane = tid & 63;
  const int n = lane & 15, quad = lane >> 4;
  const int wm = wave >> 1, wn = wave & 1;
  const int m0 = (blockIdx.x >> 3) * 128;
  const int n0 = (blockIdx.x & 7) * 128;
  const int srow = tid >> 1;
  const int soff = (tid & 1) * 32;

  f32x4 acc[4][4] = {};
  const uint4* ga = (const uint4*)(Ah + (long)(m0 + srow) * FFNq + soff);
  const uint4* gb = (const uint4*)(Bh + (long)(n0 + srow) * FFNq + soff);
  uint4* wa = (uint4*)(La + srow * 72 + soff);
  uint4* wb = (uint4*)(Lb + srow * 72 + soff);

  for (int k0 = 0; k0 < FFNq; k0 += 64) {
    uint4 a0 = ga[0], a1 = ga[1], a2 = ga[2], a3 = ga[3];
    uint4 b0 = gb[0], b1 = gb[1], b2 = gb[2], b3 = gb[3];
    ga += 8;
    gb += 8;
    __syncthreads();  // previous iteration's LDS reads done
    wa[0] = a0; wa[1] = a1; wa[2] = a2; wa[3] = a3;
    wb[0] = b0; wb[1] = b1; wb[2] = b2; wb[3] = b3;
    __syncthreads();
#pragma unroll
    for (int c = 0; c < 2; ++c) {
      f16x8 af[4], bf[4];
#pragma unroll
      for (int i = 0; i < 4; ++i) {
        af[i] = *(const f16x8*)(La + (wm * 64 + i * 16 + n) * 72 + c * 32 + quad * 8);
        bf[i] = *(const f16x8*)(Lb + (wn * 64 + i * 16 + n) * 72 + c * 32 + quad * 8);
      }
#pragma unroll
      for (int i = 0; i < 4; ++i)
#pragma unroll
        for (int j = 0; j < 4; ++j) acc[i][j] = MFMA(af[i], bf[j], acc[i][j]);
    }
  }
#pragma unroll
  for (int i = 0; i < 4; ++i) {
    const int row = m0 + wm * 64 + i * 16 + quad * 4;
#pragma unroll
    for (int j = 0; j < 4; ++j) {
      float* cp = C + (long)row * Eq + n0 + wn * 64 + j * 16 + n;
      cp[0] = acc[i][j][0];
      cp[Eq] = acc[i][j][1];
      cp[2 * Eq] = acc[i][j][2];
      cp[3 * Eq] = acc[i][j][3];
    }
  }
}

// ---------------- LN2: out = LN(h + ffn + b2) ----------------
__global__ void k_ln2(const float* __restrict__ hin, const float* __restrict__ ffn,
                      const float* __restrict__ b2, const float* __restrict__ g,
                      const float* __restrict__ be, float* __restrict__ out) {
  const long t = blockIdx.x;
  const int tid = threadIdx.x;
  float4 hv = ((const float4*)(hin + t * Eq))[tid];
  float4 fv = ((const float4*)(ffn + t * Eq))[tid];
  float4 b2v = ((const float4*)b2)[tid];
  float4 v = make_float4(hv.x + fv.x + b2v.x, hv.y + fv.y + b2v.y,
                         hv.z + fv.z + b2v.z, hv.w + fv.w + b2v.w);
  float s = v.x + v.y + v.z + v.w;
  float s2 = v.x * v.x + v.y * v.y + v.z * v.z + v.w * v.w;
#pragma unroll
  for (int o = 1; o < 64; o <<= 1) {
    s += __shfl_xor(s, o);
    s2 += __shfl_xor(s2, o);
  }
  __shared__ float red[8];
  const int wv = tid >> 6, ln = tid & 63;
  if (ln == 0) { red[wv] = s; red[4 + wv] = s2; }
  __syncthreads();
  s = red[0] + red[1] + red[2] + red[3];
  s2 = red[4] + red[5] + red[6] + red[7];
  const float mu = s * (1.f / Eq);
  const float var = s2 * (1.f / Eq) - mu * mu;
  const float rstd = rsqrtf(var + 1e-5f);
  float4 gv = ((const float4*)g)[tid];
  float4 bv = ((const float4*)be)[tid];
  float4 o;
  o.x = (v.x - mu) * rstd * gv.x + bv.x;
  o.y = (v.y - mu) * rstd * gv.y + bv.y;
  o.z = (v.z - mu) * rstd * gv.z + bv.z;
  o.w = (v.w - mu) * rstd * gv.w + bv.w;
  ((float4*)(out + t * Eq))[tid] = o;
}

extern "C" void kernel_launch(void* const* d_in, const int* in_sizes, int n_in,
                              void* d_out, int out_size, void* d_ws, size_t ws_size,
                              hipStream_t stream) {
  const float* x = (const float*)d_in[0];
  const float* theta = (const float*)d_in[1];
  const float* w1 = (const float*)d_in[2];
  const float* b1 = (const float*)d_in[3];
  const float* w2 = (const float*)d_in[4];
  const float* b2 = (const float*)d_in[5];
  const float* g1 = (const float*)d_in[6];
  const float* be1 = (const float*)d_in[7];
  const float* g2 = (const float*)d_in[8];
  const float* be2 = (const float*)d_in[9];
  float* out = (float*)d_out;

  char* ws = (char*)d_ws;
  float* attn = (float*)(ws);                    // 33554432 B
  float* h = (float*)(ws + 33554432);            // 33554432 B
  float* ffn = (float*)(ws + 67108864);          // 33554432 B
  u16* hid = (u16*)(ws + 100663296);             // 67108864 B
  u16* w2h = (u16*)(ws + 167772160);             //  8388608 B
  float* qout = (float*)(ws + 176160768);        //   262144 B  (total ~168 MiB)

  k_cvt<<<2048, 256, 0, stream>>>(w2, (uint4*)w2h, (Eq * FFNq) / 8);
  k_attn<<<Bq * Hq * (Sq / 128), 256, 0, stream>>>(x, attn);
  k_ln1<<<Bq * Sq, 256, 0, stream>>>(x, attn, g1, be1, theta, h, qout);
  k_hid<<<(Bq * Sq / 256) * (FFNq / 64), 256, 0, stream>>>(qout, w1, b1, hid);
  k_gemm<<<(Bq * Sq / 128) * (Eq / 128), 256, 0, stream>>>(hid, w2h, ffn);
  k_ln2<<<Bq * Sq, 256, 0, stream>>>(h, ffn, b2, g2, be2, out);
}

// Round 2
// 356.473 us; speedup vs baseline: 1.1087x; 1.1087x over previous
//
#include <hip/hip_runtime.h>

// TransformerBlockQuantum: attention(Q=K=V=x) -> LN1 -> quantum FFN -> LN2
// Round 1: fp16 pre-pass + global_load_lds staging + XOR-swizzled LDS tiles +
// diagonal-shift softmax (no online max; shift = |x_q|^2/8 = the diagonal score).

#define Bq 4
#define Sq 2048
#define Eq 1024
#define Hq 16
#define DKq 64
#define FFNq 4096
#define NQq 8
#define LOG2E 1.44269504f

typedef unsigned int u32;
typedef unsigned short u16;
typedef _Float16 f16;
typedef f16 f16x8 __attribute__((ext_vector_type(8)));
typedef float f32x4 __attribute__((ext_vector_type(4)));

#if __has_builtin(__builtin_amdgcn_exp2f)
#define EXP2F __builtin_amdgcn_exp2f
#else
#define EXP2F exp2f
#endif

#define MFMA(a, b, c) __builtin_amdgcn_mfma_f32_16x16x32_f16((a), (b), (c), 0, 0, 0)

// async global->LDS, 16B per lane; LDS dest = base + lane*16 (wave-uniform base)
#define GLL(g, l)                                                          \
  __builtin_amdgcn_global_load_lds(                                        \
      (const __attribute__((address_space(1))) u32*)(g),                   \
      (__attribute__((address_space(3))) u32*)(l), 16, 0, 0)

__device__ __forceinline__ u16 f2h(float x) {
  f16 t = (f16)x;
  return __builtin_bit_cast(u16, t);
}
__device__ __forceinline__ u32 pack2h(float lo, float hi) {
  return (u32)f2h(lo) | ((u32)f2h(hi) << 16);
}

union F8 { f16x8 v; u32 w[4]; u16 h[8]; f16 e[8]; };

// ---------------- fp32 -> fp16 converter (w2) ----------------
__global__ void k_cvt(const float* __restrict__ src, uint4* __restrict__ dst, int n8) {
  int i = blockIdx.x * 256 + threadIdx.x;
  if (i >= n8) return;
  const float4* s = (const float4*)src + 2 * (long)i;
  float4 a = s[0], b = s[1];
  uint4 r;
  r.x = pack2h(a.x, a.y);
  r.y = pack2h(a.z, a.w);
  r.z = pack2h(b.x, b.y);
  r.w = pack2h(b.z, b.w);
  dst[i] = r;
}

// ---------------- prep: x fp32 -> xh fp16 (row-major) + xt fp16 ([b,h,d,s]) ----
__global__ void k_prep(const float* __restrict__ x, u16* __restrict__ xh,
                       u16* __restrict__ xt) {
  __shared__ u16 tile[64 * 72];
  const int tid = threadIdx.x;
  const int bx = blockIdx.x;
  const int sb = bx & 31, bh = bx >> 5;
  const int b = bh >> 4, h = bh & 15;
  const int s0 = sb * 64;
  const int r = tid >> 2, cq = tid & 3;
  const float* xp = x + ((long)(b * Sq + s0 + r)) * Eq + h * 64 + cq * 16;
  float4 f0 = ((const float4*)xp)[0], f1 = ((const float4*)xp)[1];
  float4 f2 = ((const float4*)xp)[2], f3 = ((const float4*)xp)[3];
  u32 w[8];
  w[0] = pack2h(f0.x, f0.y); w[1] = pack2h(f0.z, f0.w);
  w[2] = pack2h(f1.x, f1.y); w[3] = pack2h(f1.z, f1.w);
  w[4] = pack2h(f2.x, f2.y); w[5] = pack2h(f2.z, f2.w);
  w[6] = pack2h(f3.x, f3.y); w[7] = pack2h(f3.z, f3.w);
  uint4* xo = (uint4*)(xh + ((long)(b * Sq + s0 + r)) * Eq + h * 64 + cq * 16);
  xo[0] = make_uint4(w[0], w[1], w[2], w[3]);
  xo[1] = make_uint4(w[4], w[5], w[6], w[7]);
  uint4* tp = (uint4*)(tile + r * 72 + cq * 16);
  tp[0] = make_uint4(w[0], w[1], w[2], w[3]);
  tp[1] = make_uint4(w[4], w[5], w[6], w[7]);
  __syncthreads();
  const int d = tid >> 2, rq = tid & 3;
  u32 o[8];
#pragma unroll
  for (int i = 0; i < 8; ++i) {
    u32 lo = tile[(rq * 16 + 2 * i) * 72 + d];
    u32 hi = tile[(rq * 16 + 2 * i + 1) * 72 + d];
    o[i] = lo | (hi << 16);
  }
  uint4* to = (uint4*)(xt + ((long)(bh * 64 + d)) * Sq + s0 + rq * 16);
  to[0] = make_uint4(o[0], o[1], o[2], o[3]);
  to[1] = make_uint4(o[4], o[5], o[6], o[7]);
}

// ---------------- flash attention ----------------
// grid = B*H*(S/256) = 512 blocks, 256 threads; each wave: 64 queries.
// ST[key][q] (transposed scores); softmax shift = diagonal score (per-lane,
// no cross-lane reduction in the k-loop); O^T[d][q] += V^T x P.
// All LDS tiles unpadded 64-halves rows, 16B chunks XOR-swizzled by (row&7).
__global__ __launch_bounds__(256, 2) void k_attn(const u16* __restrict__ xh,
                                                 const u16* __restrict__ xt,
                                                 float* __restrict__ attn) {
  __shared__ __align__(16) u16 lds[24576];  // Kl 8KB + Vt 8KB + P 4x8KB = 48KB
  u16* Kl = lds;
  u16* Vt = lds + 4096;
  u16* Pl = lds + 8192;

  const int tid = threadIdx.x;
  const int wave = tid >> 6, lane = tid & 63;
  const int n = lane & 15, quad = lane >> 4;

  const int bx = blockIdx.x;
  const int qb = bx & 7, bh = bx >> 3;
  const int b = bh >> 4, h = bh & 15;

  const u16* xh_bh = xh + (long)b * Sq * Eq + h * 64;  // row stride Eq halves
  const u16* xt_bh = xt + (long)bh * 64 * Sq;          // row stride Sq halves

  // Q fragments (B-operand: col q = lane&15, k(d) = quad*8+j (+32c)), scaled
  // by 1/sqrt(DK)=0.125; diagonal shift = 0.125*|x_q|^2 per lane.
  F8 qf[4][2];
  float shift[4], lrow[4] = {0.f, 0.f, 0.f, 0.f};
#pragma unroll
  for (int nt = 0; nt < 4; ++nt) {
    const int q = qb * 256 + wave * 64 + nt * 16 + n;
    const u16* qp = xh_bh + (long)q * Eq + quad * 8;
    F8 a, c;
    a.v = *(const f16x8*)qp;
    c.v = *(const f16x8*)(qp + 32);
    float s2 = 0.f;
#pragma unroll
    for (int i = 0; i < 8; ++i) {
      float va = (float)a.e[i], vc = (float)c.e[i];
      s2 += va * va + vc * vc;
      qf[nt][0].e[i] = a.e[i] * (f16)0.125f;
      qf[nt][1].e[i] = c.e[i] * (f16)0.125f;
    }
    s2 += __shfl_xor(s2, 16);
    s2 += __shfl_xor(s2, 32);
    shift[nt] = 0.125f * s2;
  }

  // staging: wave handles 8-row groups {2w, 2w+1} of Kl and Vt
  const int r8 = lane >> 3;
  const int cl = (lane & 7) ^ r8;  // logical chunk fetched into physical lane&7
  const u16* gK0 = xh_bh + (long)(wave * 16 + r8) * Eq + cl * 8;
  const u16* gK1 = gK0 + 8 * Eq;
  const u16* gV0 = xt_bh + (long)(wave * 16 + r8) * Sq + cl * 8;
  const u16* gV1 = gV0 + 8 * Sq;
  u16* lK0 = Kl + wave * 1024;
  u16* lK1 = lK0 + 512;
  u16* lV0 = Vt + wave * 1024;
  u16* lV1 = lV0 + 512;

  f32x4 O[4][4] = {};
  u16* Pw = Pl + wave * 4096;

  for (int kb = 0; kb < Sq / 64; ++kb) {
    __syncthreads();  // all waves done reading previous K/V tiles
    GLL(gK0, lK0);
    GLL(gK1, lK1);
    GLL(gV0, lV0);
    GLL(gV1, lV1);
    gK0 += 64 * Eq; gK1 += 64 * Eq;
    gV0 += 64; gV1 += 64;
    __syncthreads();  // vmcnt(0) drain before barrier -> tiles ready

    // QK^T: ST[nt][mt]; C-layout: key = mt*16 + quad*4 + r, q = nt*16 + n
    f32x4 ST[4][4] = {};
#pragma unroll
    for (int mt = 0; mt < 4; ++mt) {
#pragma unroll
      for (int c = 0; c < 2; ++c) {
        f16x8 af = *(const f16x8*)(Kl + (mt * 16 + n) * 64 +
                                   (((c * 4 + quad) ^ (n & 7)) * 8));
#pragma unroll
        for (int nt = 0; nt < 4; ++nt)
          ST[nt][mt] = MFMA(af, qf[nt][c].v, ST[nt][mt]);
      }
    }

    // softmax with fixed diagonal shift: p = exp(s - shift); write P[q][k]
#pragma unroll
    for (int nt = 0; nt < 4; ++nt) {
      const float sh = shift[nt];
      float ls = 0.f;
#pragma unroll
      for (int mt = 0; mt < 4; ++mt) {
        float p0 = EXP2F((ST[nt][mt][0] - sh) * LOG2E);
        float p1 = EXP2F((ST[nt][mt][1] - sh) * LOG2E);
        float p2 = EXP2F((ST[nt][mt][2] - sh) * LOG2E);
        float p3 = EXP2F((ST[nt][mt][3] - sh) * LOG2E);
        ls += (p0 + p1) + (p2 + p3);
        const int ch = 2 * mt + (quad >> 1);  // 16B chunk holding k=mt*16+quad*4
        *(uint2*)(Pw + nt * 1024 + n * 64 + ((ch ^ (n & 7)) * 8) + (quad & 1) * 4) =
            make_uint2(pack2h(p0, p1), pack2h(p2, p3));
      }
      lrow[nt] += ls;
    }

    // PV: O^T[d][q] += V^T x P
#pragma unroll
    for (int c = 0; c < 2; ++c) {
      const int pc = ((c * 4 + quad) ^ (n & 7)) * 8;
      f16x8 pf[4];
#pragma unroll
      for (int nt = 0; nt < 4; ++nt)
        pf[nt] = *(const f16x8*)(Pw + nt * 1024 + n * 64 + pc);
#pragma unroll
      for (int dt = 0; dt < 4; ++dt) {
        f16x8 vf = *(const f16x8*)(Vt + (dt * 16 + n) * 64 + pc);
#pragma unroll
        for (int nt = 0; nt < 4; ++nt) O[nt][dt] = MFMA(vf, pf[nt], O[nt][dt]);
      }
    }
  }

  // epilogue: single l-reduction (across the 4 quads), then store
#pragma unroll
  for (int nt = 0; nt < 4; ++nt) {
    float l = lrow[nt];
    l += __shfl_xor(l, 16);
    l += __shfl_xor(l, 32);
    const float inv = 1.0f / l;
    const int q = qb * 256 + wave * 64 + nt * 16 + n;
    float* op = attn + (long)b * Sq * Eq + (long)q * Eq + h * 64;
#pragma unroll
    for (int dt = 0; dt < 4; ++dt)
#pragma unroll
      for (int r = 0; r < 4; ++r)
        op[dt * 16 + quad * 4 + r] = O[nt][dt][r] * inv;
  }
}

// ---------------- LN1 (+residual) + quantum qout ----------------
__global__ void k_ln1(const float* __restrict__ x, const float* __restrict__ attn,
                      const float* __restrict__ g, const float* __restrict__ be,
                      const float* __restrict__ theta, float* __restrict__ hout,
                      float* __restrict__ qout) {
  const long t = blockIdx.x;
  const int tid = threadIdx.x;
  float4 xv = ((const float4*)(x + t * Eq))[tid];
  float4 av = ((const float4*)(attn + t * Eq))[tid];
  float4 v = make_float4(xv.x + av.x, xv.y + av.y, xv.z + av.z, xv.w + av.w);
  float s = v.x + v.y + v.z + v.w;
  float s2 = v.x * v.x + v.y * v.y + v.z * v.z + v.w * v.w;
#pragma unroll
  for (int o = 1; o < 64; o <<= 1) {
    s += __shfl_xor(s, o);
    s2 += __shfl_xor(s2, o);
  }
  __shared__ float red[8];
  const int wv = tid >> 6, ln = tid & 63;
  if (ln == 0) { red[wv] = s; red[4 + wv] = s2; }
  __syncthreads();
  s = red[0] + red[1] + red[2] + red[3];
  s2 = red[4] + red[5] + red[6] + red[7];
  const float mu = s * (1.f / Eq);
  const float var = s2 * (1.f / Eq) - mu * mu;
  const float rstd = rsqrtf(var + 1e-5f);
  float4 gv = ((const float4*)g)[tid];
  float4 bv = ((const float4*)be)[tid];
  float4 o;
  o.x = (v.x - mu) * rstd * gv.x + bv.x;
  o.y = (v.y - mu) * rstd * gv.y + bv.y;
  o.z = (v.z - mu) * rstd * gv.z + bv.z;
  o.w = (v.w - mu) * rstd * gv.w + bv.w;
  ((float4*)(hout + t * Eq))[tid] = o;
  if (tid < 2) {
    float hv[4] = {o.x, o.y, o.z, o.w};
#pragma unroll
    for (int i = 0; i < 4; ++i) {
      int j = tid * 4 + i;
      qout[t * NQq + j] = cosf(hv[i]) * cosf(theta[j]);
    }
  }
}

// ---------------- hid = relu(qout . w1^T + b1), fp16 out ----------------
__global__ void k_hid(const float* __restrict__ qout, const float* __restrict__ w1,
                      const float* __restrict__ b1, u16* __restrict__ hid) {
  __shared__ float qs[256][8];
  const int tid = threadIdx.x;
  const int fb = blockIdx.x & 63, tb = blockIdx.x >> 6;
  const int f0 = fb * 64, t0 = tb * 256;
  {
    const float4* qp = (const float4*)(qout + (long)(t0 + tid) * NQq);
    float4 q0 = qp[0], q1 = qp[1];
    *(float4*)&qs[tid][0] = q0;
    *(float4*)&qs[tid][4] = q1;
  }
  __syncthreads();
  const int wave = tid >> 6, lane = tid & 63;
  const int f = f0 + lane;
  const float4* wp = (const float4*)(w1 + (long)f * NQq);
  float4 wa = wp[0], wb = wp[1];
  const float bb = b1[f];
  const int trow = wave * 64;
  u16* op = hid + (long)(t0 + trow) * FFNq + f;
#pragma unroll 4
  for (int i = 0; i < 64; ++i) {
    const float* q = qs[trow + i];
    float acc = bb + q[0] * wa.x + q[1] * wa.y + q[2] * wa.z + q[3] * wa.w +
                q[4] * wb.x + q[5] * wb.y + q[6] * wb.z + q[7] * wb.w;
    acc = fmaxf(acc, 0.f);
    op[(long)i * FFNq] = f2h(acc);
  }
}

// ---------------- GEMM: ffn[8192,1024] = hid x w2^T ----------------
// 128x128 tile, BK=64; global_load_lds staging into swizzled unpadded tiles.
__global__ __launch_bounds__(256) void k_gemm(const u16* __restrict__ Ah,
                                              const u16* __restrict__ Bh,
                                              float* __restrict__ C) {
  __shared__ __align__(16) u16 lds[16384];  // La 16KB + Lb 16KB
  u16* La = lds;
  u16* Lb = lds + 8192;
  const int tid = threadIdx.x;
  const int wave = tid >> 6, lane = tid & 63;
  const int n = lane & 15, quad = lane >> 4;
  const int wm = wave >> 1, wn = wave & 1;
  const int m0 = (blockIdx.x >> 3) * 128;
  const int n0 = (blockIdx.x & 7) * 128;
  const int r8 = lane >> 3;
  const int cl = (lane & 7) ^ r8;

  const u16* gA[4];
  const u16* gB[4];
  u16* lA[4];
  u16* lB[4];
#pragma unroll
  for (int j = 0; j < 4; ++j) {
    const int row = wave * 32 + j * 8;
    gA[j] = Ah + (long)(m0 + row + r8) * FFNq + cl * 8;
    gB[j] = Bh + (long)(n0 + row + r8) * FFNq + cl * 8;
    lA[j] = La + row * 64;
    lB[j] = Lb + row * 64;
  }

  f32x4 acc[4][4] = {};
  for (int k0 = 0; k0 < FFNq; k0 += 64) {
    __syncthreads();
#pragma unroll
    for (int j = 0; j < 4; ++j) {
      GLL(gA[j], lA[j]);
      GLL(gB[j], lB[j]);
      gA[j] += 64;
      gB[j] += 64;
    }
    __syncthreads();
#pragma unroll
    for (int c = 0; c < 2; ++c) {
      f16x8 af[4], bf[4];
#pragma unroll
      for (int i = 0; i < 4; ++i) {
        const int ra = wm * 64 + i * 16 + n;
        const int rb = wn * 64 + i * 16 + n;
        af[i] = *(const f16x8*)(La + ra * 64 + (((c * 4 + quad) ^ (n & 7)) * 8));
        bf[i] = *(const f16x8*)(Lb + rb * 64 + (((c * 4 + quad) ^ (n & 7)) * 8));
      }
#pragma unroll
      for (int i = 0; i < 4; ++i)
#pragma unroll
        for (int j = 0; j < 4; ++j) acc[i][j] = MFMA(af[i], bf[j], acc[i][j]);
    }
  }
#pragma unroll
  for (int i = 0; i < 4; ++i) {
    const int row = m0 + wm * 64 + i * 16 + quad * 4;
#pragma unroll
    for (int j = 0; j < 4; ++j) {
      float* cp = C + (long)row * Eq + n0 + wn * 64 + j * 16 + n;
      cp[0] = acc[i][j][0];
      cp[Eq] = acc[i][j][1];
      cp[2 * Eq] = acc[i][j][2];
      cp[3 * Eq] = acc[i][j][3];
    }
  }
}

// ---------------- LN2: out = LN(h + ffn + b2) ----------------
__global__ void k_ln2(const float* __restrict__ hin, const float* __restrict__ ffn,
                      const float* __restrict__ b2, const float* __restrict__ g,
                      const float* __restrict__ be, float* __restrict__ out) {
  const long t = blockIdx.x;
  const int tid = threadIdx.x;
  float4 hv = ((const float4*)(hin + t * Eq))[tid];
  float4 fv = ((const float4*)(ffn + t * Eq))[tid];
  float4 b2v = ((const float4*)b2)[tid];
  float4 v = make_float4(hv.x + fv.x + b2v.x, hv.y + fv.y + b2v.y,
                         hv.z + fv.z + b2v.z, hv.w + fv.w + b2v.w);
  float s = v.x + v.y + v.z + v.w;
  float s2 = v.x * v.x + v.y * v.y + v.z * v.z + v.w * v.w;
#pragma unroll
  for (int o = 1; o < 64; o <<= 1) {
    s += __shfl_xor(s, o);
    s2 += __shfl_xor(s2, o);
  }
  __shared__ float red[8];
  const int wv = tid >> 6, ln = tid & 63;
  if (ln == 0) { red[wv] = s; red[4 + wv] = s2; }
  __syncthreads();
  s = red[0] + red[1] + red[2] + red[3];
  s2 = red[4] + red[5] + red[6] + red[7];
  const float mu = s * (1.f / Eq);
  const float var = s2 * (1.f / Eq) - mu * mu;
  const float rstd = rsqrtf(var + 1e-5f);
  float4 gv = ((const float4*)g)[tid];
  float4 bv = ((const float4*)be)[tid];
  float4 o;
  o.x = (v.x - mu) * rstd * gv.x + bv.x;
  o.y = (v.y - mu) * rstd * gv.y + bv.y;
  o.z = (v.z - mu) * rstd * gv.z + bv.z;
  o.w = (v.w - mu) * rstd * gv.w + bv.w;
  ((float4*)(out + t * Eq))[tid] = o;
}

extern "C" void kernel_launch(void* const* d_in, const int* in_sizes, int n_in,
                              void* d_out, int out_size, void* d_ws, size_t ws_size,
                              hipStream_t stream) {
  const float* x = (const float*)d_in[0];
  const float* theta = (const float*)d_in[1];
  const float* w1 = (const float*)d_in[2];
  const float* b1 = (const float*)d_in[3];
  const float* w2 = (const float*)d_in[4];
  const float* b2 = (const float*)d_in[5];
  const float* g1 = (const float*)d_in[6];
  const float* be1 = (const float*)d_in[7];
  const float* g2 = (const float*)d_in[8];
  const float* be2 = (const float*)d_in[9];
  float* out = (float*)d_out;

  char* ws = (char*)d_ws;
  float* attn = (float*)(ws);                        // 32 MB
  float* h = (float*)(ws + 33554432);                // 32 MB
  u16* xh = (u16*)(ws + 67108864);                   // 16 MB } dead after k_attn,
  u16* xt = (u16*)(ws + 83886080);                   // 16 MB } reused as ffn
  float* ffn = (float*)(ws + 67108864);              // 32 MB (aliases xh/xt)
  u16* hid = (u16*)(ws + 100663296);                 // 64 MB
  u16* w2h = (u16*)(ws + 167772160);                 //  8 MB
  float* qout = (float*)(ws + 176160768);            //  1 MB

  k_prep<<<Bq * Hq * (Sq / 64), 256, 0, stream>>>(x, xh, xt);
  k_cvt<<<2048, 256, 0, stream>>>(w2, (uint4*)w2h, (Eq * FFNq) / 8);
  k_attn<<<Bq * Hq * (Sq / 256), 256, 0, stream>>>(xh, xt, attn);
  k_ln1<<<Bq * Sq, 256, 0, stream>>>(x, attn, g1, be1, theta, h, qout);
  k_hid<<<(Bq * Sq / 256) * (FFNq / 64), 256, 0, stream>>>(qout, w1, b1, hid);
  k_gemm<<<(Bq * Sq / 128) * (Eq / 128), 256, 0, stream>>>(hid, w2h, ffn);
  k_ln2<<<Bq * Sq, 256, 0, stream>>>(h, ffn, b2, g2, be2, out);
}

// Round 4
// 316.870 us; speedup vs baseline: 1.2473x; 1.1250x over previous
//
#include <hip/hip_runtime.h>

// TransformerBlockQuantum: attention(Q=K=V=x) -> LN1 -> quantum FFN -> LN2
// Round 3b: single-barrier double-buffered GLL prefetch (attn+gemm), XCD-aware
// attn swizzle, softmax shift folded into MFMA C-init, fp16 intermediates.
// (fix: cvt_pkrtz returns __fp16x2, bit_cast via matching type)

#define Bq 4
#define Sq 2048
#define Eq 1024
#define Hq 16
#define DKq 64
#define FFNq 4096
#define NQq 8
#define LOG2E 1.44269504f

typedef unsigned int u32;
typedef unsigned short u16;
typedef _Float16 f16;
typedef f16 f16x8 __attribute__((ext_vector_type(8)));
typedef __fp16 fp16x2 __attribute__((ext_vector_type(2)));
typedef float f32x4 __attribute__((ext_vector_type(4)));

#if __has_builtin(__builtin_amdgcn_exp2f)
#define EXP2F __builtin_amdgcn_exp2f
#else
#define EXP2F exp2f
#endif

#define MFMA(a, b, c) __builtin_amdgcn_mfma_f32_16x16x32_f16((a), (b), (c), 0, 0, 0)

// async global->LDS, 16B per lane; LDS dest = base + lane*16 (wave-uniform base)
#define GLL(g, l)                                                          \
  __builtin_amdgcn_global_load_lds(                                        \
      (const __attribute__((address_space(1))) u32*)(g),                   \
      (__attribute__((address_space(3))) u32*)(l), 16, 0, 0)

__device__ __forceinline__ u16 f2h(float x) {
  f16 t = (f16)x;
  return __builtin_bit_cast(u16, t);
}
__device__ __forceinline__ float h2f(u16 w) {
  return (float)__builtin_bit_cast(f16, w);
}
#if __has_builtin(__builtin_amdgcn_cvt_pkrtz)
__device__ __forceinline__ u32 pkrtz(float a, float b) {
  fp16x2 r = __builtin_amdgcn_cvt_pkrtz(a, b);
  return __builtin_bit_cast(u32, r);
}
#else
__device__ __forceinline__ u32 pkrtz(float a, float b) {
  return (u32)f2h(a) | ((u32)f2h(b) << 16);
}
#endif

union F8 { f16x8 v; u32 w[4]; u16 h[8]; f16 e[8]; };

// ---------------- fp32 -> fp16 converter (w2) ----------------
__global__ void k_cvt(const float* __restrict__ src, uint4* __restrict__ dst, int n8) {
  int i = blockIdx.x * 256 + threadIdx.x;
  if (i >= n8) return;
  const float4* s = (const float4*)src + 2 * (long)i;
  float4 a = s[0], b = s[1];
  uint4 r;
  r.x = pkrtz(a.x, a.y);
  r.y = pkrtz(a.z, a.w);
  r.z = pkrtz(b.x, b.y);
  r.w = pkrtz(b.z, b.w);
  dst[i] = r;
}

// ---------------- prep: x fp32 -> xh fp16 (row-major) + xt fp16 ([b,h,d,s]) ----
__global__ void k_prep(const float* __restrict__ x, u16* __restrict__ xh,
                       u16* __restrict__ xt) {
  __shared__ u16 tile[64 * 72];
  const int tid = threadIdx.x;
  const int bx = blockIdx.x;
  const int sb = bx & 31, bh = bx >> 5;
  const int b = bh >> 4, h = bh & 15;
  const int s0 = sb * 64;
  const int r = tid >> 2, cq = tid & 3;
  const float* xp = x + ((long)(b * Sq + s0 + r)) * Eq + h * 64 + cq * 16;
  float4 f0 = ((const float4*)xp)[0], f1 = ((const float4*)xp)[1];
  float4 f2 = ((const float4*)xp)[2], f3 = ((const float4*)xp)[3];
  u32 w[8];
  w[0] = pkrtz(f0.x, f0.y); w[1] = pkrtz(f0.z, f0.w);
  w[2] = pkrtz(f1.x, f1.y); w[3] = pkrtz(f1.z, f1.w);
  w[4] = pkrtz(f2.x, f2.y); w[5] = pkrtz(f2.z, f2.w);
  w[6] = pkrtz(f3.x, f3.y); w[7] = pkrtz(f3.z, f3.w);
  uint4* xo = (uint4*)(xh + ((long)(b * Sq + s0 + r)) * Eq + h * 64 + cq * 16);
  xo[0] = make_uint4(w[0], w[1], w[2], w[3]);
  xo[1] = make_uint4(w[4], w[5], w[6], w[7]);
  uint4* tp = (uint4*)(tile + r * 72 + cq * 16);
  tp[0] = make_uint4(w[0], w[1], w[2], w[3]);
  tp[1] = make_uint4(w[4], w[5], w[6], w[7]);
  __syncthreads();
  const int d = tid >> 2, rq = tid & 3;
  u32 o[8];
#pragma unroll
  for (int i = 0; i < 8; ++i) {
    u32 lo = tile[(rq * 16 + 2 * i) * 72 + d];
    u32 hi = tile[(rq * 16 + 2 * i + 1) * 72 + d];
    o[i] = lo | (hi << 16);
  }
  uint4* to = (uint4*)(xt + ((long)(bh * 64 + d)) * Sq + s0 + rq * 16);
  to[0] = make_uint4(o[0], o[1], o[2], o[3]);
  to[1] = make_uint4(o[4], o[5], o[6], o[7]);
}

// ---------------- flash attention ----------------
// grid 512 = qb(8) x bh(64); bh = bx&63 so all q-blocks of a head share an XCD.
// Double-buffered K/V via GLL, ONE barrier per k-block (prefetch issued after
// the barrier; its vmcnt drain happens a full compute phase later).
// Softmax: ST initialized to -diag_shift via MFMA C operand; p = exp2(ST).
__global__ __launch_bounds__(256, 2) void k_attn(const u16* __restrict__ xh,
                                                 const u16* __restrict__ xt,
                                                 u16* __restrict__ attn) {
  __shared__ __align__(16) u16 lds[32768];  // 2 x (Kl 8KB | Vt 8KB) + P 32KB
  u16* Pl = lds + 16384;

  const int tid = threadIdx.x;
  const int wave = tid >> 6, lane = tid & 63;
  const int n = lane & 15, quad = lane >> 4;

  const int bx = blockIdx.x;
  const int qb = bx >> 6, bh = bx & 63;
  const int b = bh >> 4, h = bh & 15;

  const u16* xh_bh = xh + (long)b * Sq * Eq + h * 64;  // row stride Eq halves
  const u16* xt_bh = xt + (long)bh * 64 * Sq;          // row stride Sq halves

  // Q fragments (B-operand), scaled by 0.125*LOG2E so ST is in log2 domain.
  const float SC = 0.125f * LOG2E;
  F8 qf[4][2];
  float shift[4], lrow[4] = {0.f, 0.f, 0.f, 0.f};
#pragma unroll
  for (int nt = 0; nt < 4; ++nt) {
    const int q = qb * 256 + wave * 64 + nt * 16 + n;
    const u16* qp = xh_bh + (long)q * Eq + quad * 8;
    F8 a, c;
    a.v = *(const f16x8*)qp;
    c.v = *(const f16x8*)(qp + 32);
    float s2 = 0.f;
#pragma unroll
    for (int i = 0; i < 8; ++i) {
      float va = (float)a.e[i], vc = (float)c.e[i];
      s2 += va * va + vc * vc;
      qf[nt][0].e[i] = a.e[i] * (f16)SC;
      qf[nt][1].e[i] = c.e[i] * (f16)SC;
    }
    s2 += __shfl_xor(s2, 16);
    s2 += __shfl_xor(s2, 32);
    shift[nt] = SC * s2;  // diagonal score in log2 domain
  }

  // staging addresses (16B/lane, swizzled source chunk so LDS lands swizzled)
  const int r8 = lane >> 3;
  const int cl = (lane & 7) ^ r8;
  const u16* gK0 = xh_bh + (long)(wave * 16 + r8) * Eq + cl * 8;
  const u16* gK1 = gK0 + 8 * Eq;
  const u16* gV0 = xt_bh + (long)(wave * 16 + r8) * Sq + cl * 8;
  const u16* gV1 = gV0 + 8 * Sq;
  const int lK0 = wave * 1024, lK1 = lK0 + 512;
  const int lV0 = 4096 + wave * 1024, lV1 = lV0 + 512;

  u16* cur = lds;
  u16* nxt = lds + 8192;

  // prologue: prefetch k-block 0
  GLL(gK0, cur + lK0); GLL(gK1, cur + lK1);
  GLL(gV0, cur + lV0); GLL(gV1, cur + lV1);
  gK0 += 64 * Eq; gK1 += 64 * Eq; gV0 += 64; gV1 += 64;

  f32x4 O[4][4] = {};
  u16* Pw = Pl + wave * 4096;

  for (int kb = 0; kb < Sq / 64; ++kb) {
    __syncthreads();  // drains in-flight GLL (cur ready) + releases nxt
    if (kb < Sq / 64 - 1) {
      GLL(gK0, nxt + lK0); GLL(gK1, nxt + lK1);
      GLL(gV0, nxt + lV0); GLL(gV1, nxt + lV1);
      gK0 += 64 * Eq; gK1 += 64 * Eq; gV0 += 64; gV1 += 64;
    }
    u16* Kl = cur;
    u16* Vt = cur + 4096;

    // QK^T with C pre-initialized to -shift (log2 domain)
    f32x4 ST[4][4];
#pragma unroll
    for (int nt = 0; nt < 4; ++nt) {
      const float ms = -shift[nt];
#pragma unroll
      for (int mt = 0; mt < 4; ++mt) {
        ST[nt][mt][0] = ms; ST[nt][mt][1] = ms;
        ST[nt][mt][2] = ms; ST[nt][mt][3] = ms;
      }
    }
#pragma unroll
    for (int mt = 0; mt < 4; ++mt) {
#pragma unroll
      for (int c = 0; c < 2; ++c) {
        f16x8 af = *(const f16x8*)(Kl + (mt * 16 + n) * 64 +
                                   (((c * 4 + quad) ^ (n & 7)) * 8));
#pragma unroll
        for (int nt = 0; nt < 4; ++nt)
          ST[nt][mt] = MFMA(af, qf[nt][c].v, ST[nt][mt]);
      }
    }

    // p = exp2(ST); accumulate l; write P[q][k] (swizzled)
#pragma unroll
    for (int nt = 0; nt < 4; ++nt) {
      float ls = 0.f;
#pragma unroll
      for (int mt = 0; mt < 4; ++mt) {
        float p0 = EXP2F(ST[nt][mt][0]);
        float p1 = EXP2F(ST[nt][mt][1]);
        float p2 = EXP2F(ST[nt][mt][2]);
        float p3 = EXP2F(ST[nt][mt][3]);
        ls += (p0 + p1) + (p2 + p3);
        const int ch = 2 * mt + (quad >> 1);
        *(uint2*)(Pw + nt * 1024 + n * 64 + ((ch ^ (n & 7)) * 8) + (quad & 1) * 4) =
            make_uint2(pkrtz(p0, p1), pkrtz(p2, p3));
      }
      lrow[nt] += ls;
    }

    // PV: O^T[d][q] += V^T x P
#pragma unroll
    for (int c = 0; c < 2; ++c) {
      const int pc = ((c * 4 + quad) ^ (n & 7)) * 8;
      f16x8 pf[4];
#pragma unroll
      for (int nt = 0; nt < 4; ++nt)
        pf[nt] = *(const f16x8*)(Pw + nt * 1024 + n * 64 + pc);
#pragma unroll
      for (int dt = 0; dt < 4; ++dt) {
        f16x8 vf = *(const f16x8*)(Vt + (dt * 16 + n) * 64 + pc);
#pragma unroll
        for (int nt = 0; nt < 4; ++nt) O[nt][dt] = MFMA(vf, pf[nt], O[nt][dt]);
      }
    }
    u16* t = cur; cur = nxt; nxt = t;
  }

  // epilogue: reduce l across quads, store fp16
#pragma unroll
  for (int nt = 0; nt < 4; ++nt) {
    float l = lrow[nt];
    l += __shfl_xor(l, 16);
    l += __shfl_xor(l, 32);
    const float inv = 1.0f / l;
    const int q = qb * 256 + wave * 64 + nt * 16 + n;
    u16* op = attn + (long)b * Sq * Eq + (long)q * Eq + h * 64;
#pragma unroll
    for (int dt = 0; dt < 4; ++dt) {
      u32 w0 = pkrtz(O[nt][dt][0] * inv, O[nt][dt][1] * inv);
      u32 w1 = pkrtz(O[nt][dt][2] * inv, O[nt][dt][3] * inv);
      *(uint2*)(op + dt * 16 + quad * 4) = make_uint2(w0, w1);
    }
  }
}

// ---------------- LN1 (+residual) + quantum qout (all fp16 IO) ----------------
__global__ void k_ln1(const u16* __restrict__ xh, const u16* __restrict__ attn,
                      const float* __restrict__ g, const float* __restrict__ be,
                      const float* __restrict__ theta, u16* __restrict__ hout,
                      u16* __restrict__ qout) {
  const long t = blockIdx.x;
  const int tid = threadIdx.x;
  uint2 xw = ((const uint2*)(xh + t * Eq))[tid];
  uint2 aw = ((const uint2*)(attn + t * Eq))[tid];
  float v0 = h2f(xw.x & 0xffff) + h2f(aw.x & 0xffff);
  float v1 = h2f(xw.x >> 16) + h2f(aw.x >> 16);
  float v2 = h2f(xw.y & 0xffff) + h2f(aw.y & 0xffff);
  float v3 = h2f(xw.y >> 16) + h2f(aw.y >> 16);
  float s = (v0 + v1) + (v2 + v3);
  float s2 = v0 * v0 + v1 * v1 + v2 * v2 + v3 * v3;
#pragma unroll
  for (int o = 1; o < 64; o <<= 1) {
    s += __shfl_xor(s, o);
    s2 += __shfl_xor(s2, o);
  }
  __shared__ float red[8];
  const int wv = tid >> 6, ln = tid & 63;
  if (ln == 0) { red[wv] = s; red[4 + wv] = s2; }
  __syncthreads();
  s = red[0] + red[1] + red[2] + red[3];
  s2 = red[4] + red[5] + red[6] + red[7];
  const float mu = s * (1.f / Eq);
  const float var = s2 * (1.f / Eq) - mu * mu;
  const float rstd = rsqrtf(var + 1e-5f);
  float4 gv = ((const float4*)g)[tid];
  float4 bv = ((const float4*)be)[tid];
  float o0 = (v0 - mu) * rstd * gv.x + bv.x;
  float o1 = (v1 - mu) * rstd * gv.y + bv.y;
  float o2 = (v2 - mu) * rstd * gv.z + bv.z;
  float o3 = (v3 - mu) * rstd * gv.w + bv.w;
  ((uint2*)(hout + t * Eq))[tid] = make_uint2(pkrtz(o0, o1), pkrtz(o2, o3));
  if (tid < 2) {
    float hv[4] = {o0, o1, o2, o3};
    float q[4];
#pragma unroll
    for (int i = 0; i < 4; ++i) q[i] = cosf(hv[i]) * cosf(theta[tid * 4 + i]);
    *(uint2*)(qout + t * NQq + tid * 4) = make_uint2(pkrtz(q[0], q[1]), pkrtz(q[2], q[3]));
  }
}

// ---------------- hid = relu(qout . w1^T + b1), fp16 out ----------------
__global__ void k_hid(const u16* __restrict__ qout, const float* __restrict__ w1,
                      const float* __restrict__ b1, u16* __restrict__ hid) {
  __shared__ float qs[256][8];
  const int tid = threadIdx.x;
  const int fb = blockIdx.x & 63, tb = blockIdx.x >> 6;
  const int f0 = fb * 64, t0 = tb * 256;
  {
    uint4 qw = *(const uint4*)(qout + (long)(t0 + tid) * NQq);
    qs[tid][0] = h2f(qw.x & 0xffff); qs[tid][1] = h2f(qw.x >> 16);
    qs[tid][2] = h2f(qw.y & 0xffff); qs[tid][3] = h2f(qw.y >> 16);
    qs[tid][4] = h2f(qw.z & 0xffff); qs[tid][5] = h2f(qw.z >> 16);
    qs[tid][6] = h2f(qw.w & 0xffff); qs[tid][7] = h2f(qw.w >> 16);
  }
  __syncthreads();
  const int wave = tid >> 6, lane = tid & 63;
  const int f = f0 + lane;
  const float4* wp = (const float4*)(w1 + (long)f * NQq);
  float4 wa = wp[0], wb = wp[1];
  const float bb = b1[f];
  const int trow = wave * 64;
  u16* op = hid + (long)(t0 + trow) * FFNq + f;
#pragma unroll 4
  for (int i = 0; i < 64; ++i) {
    const float* q = qs[trow + i];
    float acc = bb + q[0] * wa.x + q[1] * wa.y + q[2] * wa.z + q[3] * wa.w +
                q[4] * wb.x + q[5] * wb.y + q[6] * wb.z + q[7] * wb.w;
    acc = fmaxf(acc, 0.f);
    op[(long)i * FFNq] = f2h(acc);
  }
}

// ---------------- GEMM: ffn[8192,1024] = hid x w2^T, fp16 out ----------------
// 128x128 tile, BK=64; double-buffered GLL, one barrier per k-iter.
__global__ __launch_bounds__(256, 2) void k_gemm(const u16* __restrict__ Ah,
                                                 const u16* __restrict__ Bh,
                                                 u16* __restrict__ C) {
  __shared__ __align__(16) u16 lds[32768];  // 2 x (La 16KB | Lb 16KB)
  const int tid = threadIdx.x;
  const int wave = tid >> 6, lane = tid & 63;
  const int n = lane & 15, quad = lane >> 4;
  const int wm = wave >> 1, wn = wave & 1;
  const int m0 = (blockIdx.x >> 3) * 128;
  const int n0 = (blockIdx.x & 7) * 128;
  const int r8 = lane >> 3;
  const int cl = (lane & 7) ^ r8;

  const u16* gA[4];
  const u16* gB[4];
  int lA[4], lB[4];
#pragma unroll
  for (int j = 0; j < 4; ++j) {
    const int row = wave * 32 + j * 8;
    gA[j] = Ah + (long)(m0 + row + r8) * FFNq + cl * 8;
    gB[j] = Bh + (long)(n0 + row + r8) * FFNq + cl * 8;
    lA[j] = row * 64;
    lB[j] = 8192 + row * 64;
  }

  u16* cur = lds;
  u16* nxt = lds + 16384;

  // prologue prefetch
#pragma unroll
  for (int j = 0; j < 4; ++j) {
    GLL(gA[j], cur + lA[j]);
    GLL(gB[j], cur + lB[j]);
    gA[j] += 64;
    gB[j] += 64;
  }

  f32x4 acc[4][4] = {};
  for (int it = 0; it < FFNq / 64; ++it) {
    __syncthreads();
    if (it < FFNq / 64 - 1) {
#pragma unroll
      for (int j = 0; j < 4; ++j) {
        GLL(gA[j], nxt + lA[j]);
        GLL(gB[j], nxt + lB[j]);
        gA[j] += 64;
        gB[j] += 64;
      }
    }
    u16* La = cur;
    u16* Lb = cur + 8192;
#pragma unroll
    for (int c = 0; c < 2; ++c) {
      f16x8 af[4], bf[4];
#pragma unroll
      for (int i = 0; i < 4; ++i) {
        const int ra = wm * 64 + i * 16 + n;
        const int rb = wn * 64 + i * 16 + n;
        af[i] = *(const f16x8*)(La + ra * 64 + (((c * 4 + quad) ^ (n & 7)) * 8));
        bf[i] = *(const f16x8*)(Lb + rb * 64 + (((c * 4 + quad) ^ (n & 7)) * 8));
      }
#pragma unroll
      for (int i = 0; i < 4; ++i)
#pragma unroll
        for (int j = 0; j < 4; ++j) acc[i][j] = MFMA(af[i], bf[j], acc[i][j]);
    }
    u16* t = cur; cur = nxt; nxt = t;
  }
#pragma unroll
  for (int i = 0; i < 4; ++i) {
    const int row = m0 + wm * 64 + i * 16 + quad * 4;
#pragma unroll
    for (int j = 0; j < 4; ++j) {
      u16* cp = C + (long)row * Eq + n0 + wn * 64 + j * 16 + n;
      cp[0] = f2h(acc[i][j][0]);
      cp[Eq] = f2h(acc[i][j][1]);
      cp[2 * Eq] = f2h(acc[i][j][2]);
      cp[3 * Eq] = f2h(acc[i][j][3]);
    }
  }
}

// ---------------- LN2: out = LN(h + ffn + b2), fp32 out ----------------
__global__ void k_ln2(const u16* __restrict__ hin, const u16* __restrict__ ffn,
                      const float* __restrict__ b2, const float* __restrict__ g,
                      const float* __restrict__ be, float* __restrict__ out) {
  const long t = blockIdx.x;
  const int tid = threadIdx.x;
  uint2 hw = ((const uint2*)(hin + t * Eq))[tid];
  uint2 fw = ((const uint2*)(ffn + t * Eq))[tid];
  float4 b2v = ((const float4*)b2)[tid];
  float v0 = h2f(hw.x & 0xffff) + h2f(fw.x & 0xffff) + b2v.x;
  float v1 = h2f(hw.x >> 16) + h2f(fw.x >> 16) + b2v.y;
  float v2 = h2f(hw.y & 0xffff) + h2f(fw.y & 0xffff) + b2v.z;
  float v3 = h2f(hw.y >> 16) + h2f(fw.y >> 16) + b2v.w;
  float s = (v0 + v1) + (v2 + v3);
  float s2 = v0 * v0 + v1 * v1 + v2 * v2 + v3 * v3;
#pragma unroll
  for (int o = 1; o < 64; o <<= 1) {
    s += __shfl_xor(s, o);
    s2 += __shfl_xor(s2, o);
  }
  __shared__ float red[8];
  const int wv = tid >> 6, ln = tid & 63;
  if (ln == 0) { red[wv] = s; red[4 + wv] = s2; }
  __syncthreads();
  s = red[0] + red[1] + red[2] + red[3];
  s2 = red[4] + red[5] + red[6] + red[7];
  const float mu = s * (1.f / Eq);
  const float var = s2 * (1.f / Eq) - mu * mu;
  const float rstd = rsqrtf(var + 1e-5f);
  float4 gv = ((const float4*)g)[tid];
  float4 bv = ((const float4*)be)[tid];
  float4 o;
  o.x = (v0 - mu) * rstd * gv.x + bv.x;
  o.y = (v1 - mu) * rstd * gv.y + bv.y;
  o.z = (v2 - mu) * rstd * gv.z + bv.z;
  o.w = (v3 - mu) * rstd * gv.w + bv.w;
  ((float4*)(out + t * Eq))[tid] = o;
}

extern "C" void kernel_launch(void* const* d_in, const int* in_sizes, int n_in,
                              void* d_out, int out_size, void* d_ws, size_t ws_size,
                              hipStream_t stream) {
  const float* x = (const float*)d_in[0];
  const float* theta = (const float*)d_in[1];
  const float* w1 = (const float*)d_in[2];
  const float* b1 = (const float*)d_in[3];
  const float* w2 = (const float*)d_in[4];
  const float* b2 = (const float*)d_in[5];
  const float* g1 = (const float*)d_in[6];
  const float* be1 = (const float*)d_in[7];
  const float* g2 = (const float*)d_in[8];
  const float* be2 = (const float*)d_in[9];
  float* out = (float*)d_out;

  char* ws = (char*)d_ws;
  u16* attn = (u16*)(ws);                      // 16 MB
  u16* h = (u16*)(ws + 16777216);              // 16 MB
  u16* xh = (u16*)(ws + 33554432);             // 16 MB
  u16* xt = (u16*)(ws + 50331648);             // 16 MB
  u16* ffn = (u16*)(ws + 67108864);            // 16 MB
  u16* hid = (u16*)(ws + 83886080);            // 64 MB
  u16* w2h = (u16*)(ws + 150994944);           //  8 MB
  u16* qout = (u16*)(ws + 159383552);          // 128 KB

  k_prep<<<Bq * Hq * (Sq / 64), 256, 0, stream>>>(x, xh, xt);
  k_cvt<<<2048, 256, 0, stream>>>(w2, (uint4*)w2h, (Eq * FFNq) / 8);
  k_attn<<<Bq * Hq * (Sq / 256), 256, 0, stream>>>(xh, xt, attn);
  k_ln1<<<Bq * Sq, 256, 0, stream>>>(xh, attn, g1, be1, theta, h, qout);
  k_hid<<<(Bq * Sq / 256) * (FFNq / 64), 256, 0, stream>>>(qout, w1, b1, hid);
  k_gemm<<<(Bq * Sq / 128) * (Eq / 128), 256, 0, stream>>>(hid, w2h, ffn);
  k_ln2<<<Bq * Sq, 256, 0, stream>>>(h, ffn, b2, g2, be2, out);
}